// Round 14
// baseline (201.112 us; speedup 1.0000x reference)
//
#include <hip/hip_runtime.h>

typedef float    f32x4 __attribute__((ext_vector_type(4)));
typedef _Float16 f16x2 __attribute__((ext_vector_type(2)));
typedef _Float16 f16x4 __attribute__((ext_vector_type(4)));
typedef _Float16 f16x8 __attribute__((ext_vector_type(8)));
typedef int      i32x4 __attribute__((ext_vector_type(4)));

namespace {
constexpr int B_ = 2, L_ = 2048, S_ = 2048, H_ = 16, E_ = 64;
constexpr int MBLK = 64;         // q rows per block (2 q-subblocks x 32)
constexpr int NT = 64;           // s-tile width
constexpr int NTILES = S_ / NT;  // 32

#define SCALE2f 0.1803368801111204f /* 0.125 * log2(e), folded into Q */
#define MBIAS2f -1.8033688e8f       /* -1e9 * 0.125 * log2(e): exp2 -> exactly 0 */

// ws layout: [0,1MiB) mask bits | Kh f16 [b,h,s,e] 8.39MB | Vh f16 [b,h,e,s'] 8.39MB
// mask bit layout inside each u64 (one 64-s chunk): bit p = 16*(s&3) + (s>>2 & 15)
// Vh s-layout: within each 64-s tile, 4-elem chunks permuted pos(8n+4h+q)=8n+2q+h
// so each PV B-frag (s-chunks 8g+qd, 8g+qd+4) is one contiguous 16B granule.
constexpr size_t KHOFF = (size_t)1 << 20;
constexpr size_t VHOFF = KHOFF + (size_t)B_ * H_ * S_ * E_ * 2;

__device__ __forceinline__ f16x2 cvt2(float a, float b) {
  return __builtin_bit_cast(f16x2, __builtin_amdgcn_cvt_pkrtz(a, b));
}
__device__ __forceinline__ int pkh(float a, float b) {
  return __builtin_bit_cast(int, __builtin_amdgcn_cvt_pkrtz(a, b));
}
union H8 { f16x8 v; i32x4 i; f16x4 h4[2]; };
union H4 { f16x4 v; f16x2 h[2]; };

#define GLOAD_LDS16(g, l)                                              \
  __builtin_amdgcn_global_load_lds(                                    \
      (const __attribute__((address_space(1))) void*)(g),              \
      (__attribute__((address_space(3))) void*)(l), 16, 0, 0)
}  // namespace

// ---- fused pre-pass: kcvt [0,2048) | maskpack [2048,4096) | vcvt [4096,5120)
extern "C" __global__ __launch_bounds__(256)
void prep_kernel(const float* __restrict__ Kg, const float* __restrict__ Vg,
                 const float* __restrict__ Mg, _Float16* __restrict__ Kh,
                 _Float16* __restrict__ Vh, unsigned long long* __restrict__ Wb) {
  __shared__ _Float16 T[64][72];
  const int bid = blockIdx.x;
  const int t   = threadIdx.x;

  if (bid < 2048) {
    // K [b,s,h,e] f32 -> Kh [b,h,s,e] f16 (h-gather)
    const int idx = bid * 256 + t;  // 8-e chunk id
    const int j = idx & 7;
    const int h = (idx >> 3) & (H_ - 1);
    const int s = (idx >> 7) & (S_ - 1);
    const int b = idx >> 18;
    const float* src = Kg + ((((size_t)b * S_ + s) * H_ + h) << 6) + j * 8;
    f32x4 x = *(const f32x4*)src, y = *(const f32x4*)(src + 4);
    i32x4 w = {pkh(x[0], x[1]), pkh(x[2], x[3]), pkh(y[0], y[1]), pkh(y[2], y[3])};
    *(i32x4*)(Kh + ((((size_t)b * H_ + h) * S_ + s) << 6) + j * 8) = w;
  } else if (bid < 4096) {
    // mask fp32 -> bits: fully-coalesced 16B/lane loads + ballot + SALU pack.
    // word bit p = 16*(s&3) + (s>>2): ballot_i bit (16j+a) -> word j bit 16i+a.
    const int wv2   = t >> 6;
    const int lane2 = t & 63;
    const size_t wave_id = (size_t)(bid - 2048) * 4 + wv2;   // [0, 8192)
    const float* mp = Mg + wave_id * 1024 + lane2 * 4;
    unsigned long long* wp = Wb + wave_id * 16;
#pragma unroll
    for (int k = 0; k < 4; ++k) {
      const f32x4 x = *(const f32x4*)(mp + k * 256);
      const unsigned long long b0 = __ballot(x[0] > 0.5f);
      const unsigned long long b1 = __ballot(x[1] > 0.5f);
      const unsigned long long b2 = __ballot(x[2] > 0.5f);
      const unsigned long long b3 = __ballot(x[3] > 0.5f);
      if (lane2 < 4) {
        const int sh = lane2 * 16;
        const unsigned long long w =
            ((b0 >> sh) & 0xFFFFull) | (((b1 >> sh) & 0xFFFFull) << 16) |
            (((b2 >> sh) & 0xFFFFull) << 32) | (((b3 >> sh) & 0xFFFFull) << 48);
        wp[k * 4 + lane2] = w;
      }
    }
  } else {
    // V [b,s,h,e] f32 -> Vh [b,h,e,s'] f16 (transpose via LDS), s-chunks
    // interleaved within each 64-s tile: dst pos 4u+k holds source chunk
    // {C, C+4, C+1, C+5}[k], C = 8*(u>>1) + 2*(u&1)  (pos(8n+4h+q)=8n+2q+h).
    const int vb = bid - 4096;  // (b,h,st)
    const int st = vb & 31;
    const int h  = (vb >> 5) & (H_ - 1);
    const int b  = vb >> 9;
    const int sl = t >> 2;
    const int e0 = (t & 3) << 4;
    const float* src = Vg + ((((size_t)b * S_ + st * 64 + sl) * H_ + h) << 6) + e0;
#pragma unroll
    for (int i = 0; i < 4; ++i) {
      f32x4 x = *(const f32x4*)(src + i * 4);
#pragma unroll
      for (int c = 0; c < 4; ++c) T[e0 + i * 4 + c][sl] = (_Float16)x[c];
    }
    __syncthreads();
    const int er = t >> 2;
    const int u  = t & 3;
    const int C  = ((u >> 1) << 3) + ((u & 1) << 1);
    _Float16* dst = Vh + (((((size_t)b * H_ + h) << 6) + er) * S_) + st * 64 + u * 16;
    H8 w;
    w.h4[0] = *(const f16x4*)&T[er][(C) * 4];
    w.h4[1] = *(const f16x4*)&T[er][(C + 4) * 4];
    *(i32x4*)dst = w.i;
    w.h4[0] = *(const f16x4*)&T[er][(C + 1) * 4];
    w.h4[1] = *(const f16x4*)&T[er][(C + 5) * 4];
    *(i32x4*)(dst + 8) = w.i;
  }
}

// s-half split in r9's EXACT register/block shape (the only one that compiles
// clean: 256 thr, 4 waves, launch_bounds(256,2), 2-m-tile state = 88 VGPR).
// MBLK=64: grid 1024; 4 waves = 2 q-subblocks (32 rows) x 2 s-halves. Each
// wave reads only its s-half (8 KB/tile vs 16). Totals vs r9: LDS reads,
// MFMA, exp2 all identical; DMA doubles (L2-absorbed, same-XCD); occupancy
// 2 -> 3 blocks/CU (LDS 48KB x3 = 144 <= 160). Clean TLP discriminator.
// r10-r13 spill lesson: any other block shape gets mis-budgeted by the
// allocator (104/108/64 VGPR + ~100MB scratch). Do not change this shape.
extern "C" __global__ __launch_bounds__(256, 2)
void fattn_kernel(const float* __restrict__ Qg, const _Float16* __restrict__ Kh,
                  const _Float16* __restrict__ Vh, const unsigned long long* __restrict__ Wb,
                  float* __restrict__ Og) {
  __shared__ __align__(16) _Float16 Ks[3][NT][64];
  __shared__ __align__(16) _Float16 Vt[3][E_][64];

  const int tid  = threadIdx.x;
  const int wv   = tid >> 6;   // 0..3
  const int lane = tid & 63;
  const int h2   = wv & 1;     // s-half: rows [h2*32, h2*32+32)
  const int wq   = wv >> 1;    // q sub-block (32 rows)
  const int qd   = lane >> 4;
  const int cl   = lane & 15;
  const int sw   = cl & 7;     // reader swizzle key (row & 7)

  // XCD-locality: bid%8 == bh%8 -> all 32 q-blocks of one (b,h) on one XCD
  const int bid = blockIdx.x;
  const int qb  = bid >> 5;
  const int bh  = bid & 31;
  const int h   = bh & (H_ - 1);
  const int b   = bh >> 4;

  const int l0 = qb * MBLK + wq * 32;  // 32 q rows per wave (2 m-tiles)

  // ---- Q fragments (B-operand of S^T = K Q^T), f16, pre-scaled by SCALE2f
  f16x8 qf[2][2];
#pragma unroll
  for (int mt = 0; mt < 2; ++mt) {
    const float* qp = Qg + ((((size_t)b * L_ + (l0 + mt * 16 + cl)) * H_ + h) << 6);
#pragma unroll
    for (int kb = 0; kb < 2; ++kb) {
      const int e0 = qd * 8 + kb * 32;
      f32x4 x = *(const f32x4*)(qp + e0);
      f32x4 y = *(const f32x4*)(qp + e0 + 4);
      x *= SCALE2f;
      y *= SCALE2f;
      H8 u;
      u.i = (i32x4){pkh(x[0], x[1]), pkh(x[2], x[3]), pkh(y[0], y[1]), pkh(y[2], y[3])};
      qf[mt][kb] = u.v;
    }
  }

  // ---- DMA lane constants: lane = 8*row_local + granule_slot
  const int rl  = lane >> 3;       // row within wave-iter (0..7)
  const int gsl = lane & 7;        // granule slot in LDS row
  const int gsw = gsl ^ rl;        // swizzled source granule (row&7 == rl)
  const _Float16* khb = Kh + ((((size_t)b * H_ + h) * S_) << 6);          // [s][e]
  const _Float16* vhb = Vh + ((((size_t)b * H_ + h) << 6) * (size_t)S_);  // [e][s']

  const unsigned long long* wbp = Wb + (((size_t)b * L_ + (l0 + cl)) << 5);

  // stage one tile's K+V via global_load_lds (16 B/lane, 2 wave-iters each)
  auto dma = [&](int buf, int t) {
#pragma unroll
    for (int p = 0; p < 2; ++p) {
      const int r0 = p * 32 + wv * 8;
      const _Float16* ksrc = khb + (((size_t)(t * 64 + r0 + rl)) << 6) + gsw * 8;
      GLOAD_LDS16(ksrc, &Ks[buf][r0][0]);
      const _Float16* vsrc = vhb + (size_t)(r0 + rl) * S_ + t * 64 + gsw * 8;
      GLOAD_LDS16(vsrc, &Vt[buf][r0][0]);
    }
  };

  const f32x4 zero4 = {0.f, 0.f, 0.f, 0.f};
  f32x4 acc[2][4];
#pragma unroll
  for (int mt = 0; mt < 2; ++mt)
#pragma unroll
    for (int et = 0; et < 4; ++et) acc[mt][et] = zero4;
  f32x4 rs4[2] = {zero4, zero4};

  // ---- prologue: regions 0 and 1 (5 VMEM each: mask + 4 gload_lds)
  unsigned long long mwcur = wbp[0];
  dma(0, 0);
  asm volatile("" ::: "memory");  // region boundary
  unsigned long long mwnext = wbp[1];
  dma(1, 1);
  asm volatile("" ::: "memory");

  int bc = 0;  // t % 3
  for (int t = 0; t < NTILES; ++t) {
    // region t landed (tile t K,V,mask); region t+1 (5 ops) stays in flight
    if (t < NTILES - 1)
      asm volatile("s_waitcnt vmcnt(5)" ::: "memory");
    else
      asm volatile("s_waitcnt vmcnt(0)" ::: "memory");
    __builtin_amdgcn_s_barrier();

    // region t+2
    unsigned long long mwnext2 = 0;
    const int bn = (bc == 2) ? 0 : bc + 1;
    if (t + 2 < NTILES) {
      const int b2 = (bn == 2) ? 0 : bn + 1;
      mwnext2 = wbp[t + 2];
      dma(b2, t + 2);
    }
    asm volatile("" ::: "memory");  // region boundary

    // ---- fused QK^T -> masked exp2 over this wave's s-half
    // bit for s = ntg*16+qd*4+r sits at p = 16r + 4*ntg + qd, ntg = h2*2+nt
    H8 pa8[2];  // per mt: slot nt of this s-half
    const _Float16* kb0 = &Ks[bc][h2 * 32][0];
    const unsigned lo = (unsigned)mwcur;
    const unsigned hi = (unsigned)(mwcur >> 32);
#pragma unroll
    for (int nt = 0; nt < 2; ++nt) {
      const _Float16* krow = kb0 + (nt * 16 + cl) * 64;
      const f16x8 a0 = *(const f16x8*)(krow + ((qd ^ sw) << 3));
      const f16x8 a1 = *(const f16x8*)(krow + (((qd + 4) ^ sw) << 3));
      f32x4 sc[2];
#pragma unroll
      for (int mt = 0; mt < 2; ++mt) {
        f32x4 c = zero4;
        c = __builtin_amdgcn_mfma_f32_16x16x32_f16(a0, qf[mt][0], c, 0, 0, 0);
        c = __builtin_amdgcn_mfma_f32_16x16x32_f16(a1, qf[mt][1], c, 0, 0, 0);
        sc[mt] = c;  // q = mt*16+cl, s = h2*32 + nt*16 + qd*4 + r
      }
      const int ntg = h2 * 2 + nt;
      const unsigned m0 = lo >> (4 * ntg + qd);  // r=0 bit0, r=1 bit16
      const unsigned m1 = hi >> (4 * ntg + qd);  // r=2 bit0, r=3 bit16
      const float bias0 = (m0 & 1u)       ? 0.f : MBIAS2f;
      const float bias1 = (m0 & 0x10000u) ? 0.f : MBIAS2f;
      const float bias2 = (m1 & 1u)       ? 0.f : MBIAS2f;
      const float bias3 = (m1 & 0x10000u) ? 0.f : MBIAS2f;
#pragma unroll
      for (int mt = 0; mt < 2; ++mt) {
        f32x4 p;
        p[0] = __builtin_amdgcn_exp2f(sc[mt][0] + bias0);
        p[1] = __builtin_amdgcn_exp2f(sc[mt][1] + bias1);
        p[2] = __builtin_amdgcn_exp2f(sc[mt][2] + bias2);
        p[3] = __builtin_amdgcn_exp2f(sc[mt][3] + bias3);
        rs4[mt] += p;
        H4 u;
        u.h[0] = cvt2(p[0], p[1]);
        u.h[1] = cvt2(p[2], p[3]);
        pa8[mt].h4[nt] = u.v;
      }
    }

    // ---- partial O += P V over s-half (interleaved Vt: one b128 per MFMA)
    const _Float16* vb0 = &Vt[bc][0][0];
#pragma unroll
    for (int et = 0; et < 4; ++et) {
      const _Float16* vrow = vb0 + (et * 16 + cl) * 64;
      const f16x8 bv = *(const f16x8*)(vrow + (((h2 * 4 + qd) ^ sw) << 3));
      acc[0][et] = __builtin_amdgcn_mfma_f32_16x16x32_f16(pa8[0].v, bv, acc[0][et], 0, 0, 0);
      acc[1][et] = __builtin_amdgcn_mfma_f32_16x16x32_f16(pa8[1].v, bv, acc[1][et], 0, 0, 0);
    }

    mwcur = mwnext;
    mwnext = mwnext2;
    bc = bn;
  }

  // ---- epilogue: combine s-half partials (plain adds), normalize, store.
  // Wave (wq,h2) keeps e-cols [h2*32, h2*32+32) (et pair h2*2, h2*2+1) and
  // sends the other et pair via LDS scratch (mt=0 in Ks area, mt=1 in Vt
  // area). All register subscripts compile-time (wave-uniform ternaries).
  float vsum[2];
#pragma unroll
  for (int mt = 0; mt < 2; ++mt) {
    float v = rs4[mt][0] + rs4[mt][1] + rs4[mt][2] + rs4[mt][3];
    v += __shfl_xor(v, 16, 64);
    v += __shfl_xor(v, 32, 64);  // per lane: this s-half's sum for q = mt*16+cl
    vsum[mt] = v;
  }

  __syncthreads();  // all tile reads done; smem reusable as scratch
  f32x4* xscr = (f32x4*)&Ks[0][0][0];  // mt=0: [(wq*2+h2)*2+ei]<<6 + lane, 8KB
  f32x4* yscr = (f32x4*)&Vt[0][0][0];  // mt=1: same layout, 8KB
  float* rscr = (float*)((char*)&Vt[0][0][0] + (8 << 10));  // [(wq*2+h2)*2+mt]*16+cl
#pragma unroll
  for (int mt = 0; mt < 2; ++mt) {
    f32x4* buf = mt ? yscr : xscr;
    const f32x4 s0 = h2 ? acc[mt][0] : acc[mt][2];  // partner's et pair
    const f32x4 s1 = h2 ? acc[mt][1] : acc[mt][3];
    buf[(((wq * 2 + h2) * 2 + 0) << 6) + lane] = s0;
    buf[(((wq * 2 + h2) * 2 + 1) << 6) + lane] = s1;
  }
  if (lane < 16) {
#pragma unroll
    for (int mt = 0; mt < 2; ++mt)
      rscr[((wq * 2 + h2) * 2 + mt) * 16 + cl] = vsum[mt];
  }
  __syncthreads();

  const int hp = 1 - h2;  // partner
#pragma unroll
  for (int mt = 0; mt < 2; ++mt) {
    f32x4* buf = mt ? yscr : xscr;
    const float vtot = vsum[mt] + rscr[((wq * 2 + hp) * 2 + mt) * 16 + cl];
    f32x4 own0 = h2 ? acc[mt][2] : acc[mt][0];   // own-column chunks
    f32x4 own1 = h2 ? acc[mt][3] : acc[mt][1];
    own0 += buf[(((wq * 2 + hp) * 2 + 0) << 6) + lane];
    own1 += buf[(((wq * 2 + hp) * 2 + 1) << 6) + lane];
#pragma unroll
    for (int r = 0; r < 4; ++r) {
      const float invq = 1.0f / __shfl(vtot, qd * 4 + r, 64);
      const int l = l0 + mt * 16 + qd * 4 + r;
      float* op = Og + ((((size_t)b * H_ + h) * L_ + l) << 6) + cl;
      op[(h2 * 2 + 0) * 16] = own0[r] * invq;
      op[(h2 * 2 + 1) * 16] = own1[r] * invq;
    }
  }
}

extern "C" void kernel_launch(void* const* d_in, const int* in_sizes, int n_in,
                              void* d_out, int out_size, void* d_ws, size_t ws_size,
                              hipStream_t stream) {
  const float* Q = (const float*)d_in[0];
  const float* K = (const float*)d_in[1];
  const float* V = (const float*)d_in[2];
  const float* M = (const float*)d_in[3];
  float* O = (float*)d_out;
  unsigned long long* Wb = (unsigned long long*)d_ws;              // 1 MiB
  _Float16* Khp = (_Float16*)((char*)d_ws + KHOFF);                // 8.39 MB
  _Float16* Vhp = (_Float16*)((char*)d_ws + VHOFF);                // 8.39 MB

  hipLaunchKernelGGL(prep_kernel, dim3(5120), dim3(256), 0, stream, K, V, M, Khp, Vhp, Wb);
  hipLaunchKernelGGL(fattn_kernel, dim3(B_ * H_ * (L_ / MBLK)), dim3(256), 0, stream,
                     Q, Khp, Vhp, Wb, O);
}

// Round 15
// 155.771 us; speedup vs baseline: 1.2911x; 1.2911x over previous
//
#include <hip/hip_runtime.h>

typedef float    f32x4 __attribute__((ext_vector_type(4)));
typedef _Float16 f16x2 __attribute__((ext_vector_type(2)));
typedef _Float16 f16x4 __attribute__((ext_vector_type(4)));
typedef _Float16 f16x8 __attribute__((ext_vector_type(8)));
typedef int      i32x4 __attribute__((ext_vector_type(4)));

namespace {
constexpr int B_ = 2, L_ = 2048, S_ = 2048, H_ = 16, E_ = 64;
constexpr int MBLK = 128;        // q rows per block (4 waves x 32)
constexpr int NT = 64;           // s-tile width
constexpr int NTILES = S_ / NT;  // 32
constexpr int NPAIRS = NTILES / 2;

#define SCALE2f 0.1803368801111204f /* 0.125 * log2(e), folded into Q */
#define MBIAS2f -1.8033688e8f       /* -1e9 * 0.125 * log2(e): exp2 -> exactly 0 */

// ws layout: [0,1MiB) mask bits | Kh f16 [b,h,s,e] 8.39MB | Vh f16 [b,h,e,s'] 8.39MB
// mask bit layout inside each u64 (one 64-s chunk): bit p = 16*(s&3) + (s>>2 & 15)
// Vh s-layout: within each 64-s tile, 4-elem chunks permuted pos(8n+4h+q)=8n+2q+h
// so that each PV B-frag (s-chunks 8ntp+qd and 8ntp+qd+4) is one contiguous 16B.
constexpr size_t KHOFF = (size_t)1 << 20;
constexpr size_t VHOFF = KHOFF + (size_t)B_ * H_ * S_ * E_ * 2;

__device__ __forceinline__ f16x2 cvt2(float a, float b) {
  return __builtin_bit_cast(f16x2, __builtin_amdgcn_cvt_pkrtz(a, b));
}
__device__ __forceinline__ int pkh(float a, float b) {
  return __builtin_bit_cast(int, __builtin_amdgcn_cvt_pkrtz(a, b));
}
union H8 { f16x8 v; i32x4 i; f16x4 h4[2]; };
union H4 { f16x4 v; f16x2 h[2]; };

#define GLOAD_LDS16(g, l)                                              \
  __builtin_amdgcn_global_load_lds(                                    \
      (const __attribute__((address_space(1))) void*)(g),              \
      (__attribute__((address_space(3))) void*)(l), 16, 0, 0)
}  // namespace

// ---- fused pre-pass: kcvt [0,2048) | maskpack [2048,4096) | vcvt [4096,5120)
extern "C" __global__ __launch_bounds__(256)
void prep_kernel(const float* __restrict__ Kg, const float* __restrict__ Vg,
                 const float* __restrict__ Mg, _Float16* __restrict__ Kh,
                 _Float16* __restrict__ Vh, unsigned long long* __restrict__ Wb) {
  __shared__ _Float16 T[64][72];
  const int bid = blockIdx.x;
  const int t   = threadIdx.x;

  if (bid < 2048) {
    // K [b,s,h,e] f32 -> Kh [b,h,s,e] f16 (h-gather)
    const int idx = bid * 256 + t;  // 8-e chunk id
    const int j = idx & 7;
    const int h = (idx >> 3) & (H_ - 1);
    const int s = (idx >> 7) & (S_ - 1);
    const int b = idx >> 18;
    const float* src = Kg + ((((size_t)b * S_ + s) * H_ + h) << 6) + j * 8;
    f32x4 x = *(const f32x4*)src, y = *(const f32x4*)(src + 4);
    i32x4 w = {pkh(x[0], x[1]), pkh(x[2], x[3]), pkh(y[0], y[1]), pkh(y[2], y[3])};
    *(i32x4*)(Kh + ((((size_t)b * H_ + h) * S_ + s) << 6) + j * 8) = w;
  } else if (bid < 4096) {
    // mask fp32 -> bits: fully-coalesced 16B/lane loads + ballot + SALU pack.
    // word bit p = 16*(s&3) + (s>>2): ballot_i bit (16j+a) -> word j bit 16i+a.
    const int wv2   = t >> 6;
    const int lane2 = t & 63;
    const size_t wave_id = (size_t)(bid - 2048) * 4 + wv2;   // [0, 8192)
    const float* mp = Mg + wave_id * 1024 + lane2 * 4;
    unsigned long long* wp = Wb + wave_id * 16;
#pragma unroll
    for (int k = 0; k < 4; ++k) {
      const f32x4 x = *(const f32x4*)(mp + k * 256);
      const unsigned long long b0 = __ballot(x[0] > 0.5f);
      const unsigned long long b1 = __ballot(x[1] > 0.5f);
      const unsigned long long b2 = __ballot(x[2] > 0.5f);
      const unsigned long long b3 = __ballot(x[3] > 0.5f);
      if (lane2 < 4) {
        const int sh = lane2 * 16;
        const unsigned long long w =
            ((b0 >> sh) & 0xFFFFull) | (((b1 >> sh) & 0xFFFFull) << 16) |
            (((b2 >> sh) & 0xFFFFull) << 32) | (((b3 >> sh) & 0xFFFFull) << 48);
        wp[k * 4 + lane2] = w;
      }
    }
  } else {
    // V [b,s,h,e] f32 -> Vh [b,h,e,s'] f16 (transpose via LDS), s-chunks
    // interleaved within each 64-s tile: dst pos 4u+k holds source chunk
    // {C, C+4, C+1, C+5}[k], C = 8*(u>>1) + 2*(u&1)  (pos(8n+4h+q)=8n+2q+h).
    const int vb = bid - 4096;  // (b,h,st)
    const int st = vb & 31;
    const int h  = (vb >> 5) & (H_ - 1);
    const int b  = vb >> 9;
    const int sl = t >> 2;
    const int e0 = (t & 3) << 4;
    const float* src = Vg + ((((size_t)b * S_ + st * 64 + sl) * H_ + h) << 6) + e0;
#pragma unroll
    for (int i = 0; i < 4; ++i) {
      f32x4 x = *(const f32x4*)(src + i * 4);
#pragma unroll
      for (int c = 0; c < 4; ++c) T[e0 + i * 4 + c][sl] = (_Float16)x[c];
    }
    __syncthreads();
    const int er = t >> 2;
    const int u  = t & 3;
    const int C  = ((u >> 1) << 3) + ((u & 1) << 1);
    _Float16* dst = Vh + (((((size_t)b * H_ + h) << 6) + er) * S_) + st * 64 + u * 16;
    H8 w;
    w.h4[0] = *(const f16x4*)&T[er][(C) * 4];
    w.h4[1] = *(const f16x4*)&T[er][(C + 4) * 4];
    *(i32x4*)dst = w.i;
    w.h4[0] = *(const f16x4*)&T[er][(C + 1) * 4];
    w.h4[1] = *(const f16x4*)&T[er][(C + 5) * 4];
    *(i32x4*)(dst + 8) = w.i;
  }
}

// FINAL (r9): pair processing, quad-buffer, counted vmcnt(10), interleaved Vt.
// PV B-frags are single b128 reads (8 per tile/wave); PV at mfma_16x16x32 via
// permuted-k (B-frag elem j at granule ntp*4+qd = s 32ntp+16*(j>=4)+4qd+(j&3),
// identical to the P fragments' sigma). Bank conflicts = 0; VGPR 88, no spill.
// r10-r14 lesson: every repartition that halves per-wave LDS reads (s-half
// splits, 64-q waves) dies in register allocation (VGPR pinned 64-108, 85-114
// MB scratch) regardless of launch_bounds/waves_per_eu hints. This source is
// the verified-clean floor of the design under this compiler.
extern "C" __global__ __launch_bounds__(256, 2)
void fattn_kernel(const float* __restrict__ Qg, const _Float16* __restrict__ Kh,
                  const _Float16* __restrict__ Vh, const unsigned long long* __restrict__ Wb,
                  float* __restrict__ Og) {
  // quad-buffer: tile t lives in buf t&3; DMA dest lane-contiguous (no pad),
  // bank safety via XOR-granule swizzle
  __shared__ __align__(16) _Float16 Ks[4][NT][64];
  __shared__ __align__(16) _Float16 Vt[4][E_][64];

  const int tid  = threadIdx.x;
  const int wv   = tid >> 6;   // 0..3
  const int lane = tid & 63;
  const int qd   = lane >> 4;
  const int cl   = lane & 15;
  const int sw   = cl & 7;     // reader swizzle key (row & 7)

  // XCD-locality: bid%8 == bh%8 -> all 16 q-blocks of one (b,h) on one XCD
  const int bid = blockIdx.x;
  const int qb  = bid >> 5;
  const int bh  = bid & 31;
  const int h   = bh & (H_ - 1);
  const int b   = bh >> 4;

  const int l0 = qb * MBLK + wv * 32;  // 32 q rows per wave (2 m-tiles)

  // ---- Q fragments (B-operand of S^T = K Q^T), f16, pre-scaled by SCALE2f
  f16x8 qf[2][2];
#pragma unroll
  for (int mt = 0; mt < 2; ++mt) {
    const float* qp = Qg + ((((size_t)b * L_ + (l0 + mt * 16 + cl)) * H_ + h) << 6);
#pragma unroll
    for (int kb = 0; kb < 2; ++kb) {
      const int e0 = qd * 8 + kb * 32;
      f32x4 x = *(const f32x4*)(qp + e0);
      f32x4 y = *(const f32x4*)(qp + e0 + 4);
      x *= SCALE2f;
      y *= SCALE2f;
      H8 u;
      u.i = (i32x4){pkh(x[0], x[1]), pkh(x[2], x[3]), pkh(y[0], y[1]), pkh(y[2], y[3])};
      qf[mt][kb] = u.v;
    }
  }

  // ---- DMA lane constants: lane = 8*row_local + granule_slot
  const int rl  = lane >> 3;       // row within wave-iter (0..7)
  const int gsl = lane & 7;        // granule slot in LDS row
  const int gsw = gsl ^ rl;        // swizzled source granule (row&7 == rl)
  const _Float16* khb = Kh + ((((size_t)b * H_ + h) * S_) << 6);          // [s][e]
  const _Float16* vhb = Vh + ((((size_t)b * H_ + h) << 6) * (size_t)S_);  // [e][s']

  const unsigned long long* wbp = Wb + (((size_t)b * L_ + (l0 + cl)) << 5);

  // stage one tile's K+V via global_load_lds (16 B/lane, 2 wave-iters each)
  auto dma = [&](int buf, int t) {
#pragma unroll
    for (int p = 0; p < 2; ++p) {
      const int r0 = p * 32 + wv * 8;
      const _Float16* ksrc = khb + (((size_t)(t * 64 + r0 + rl)) << 6) + gsw * 8;
      GLOAD_LDS16(ksrc, &Ks[buf][r0][0]);
      const _Float16* vsrc = vhb + (size_t)(r0 + rl) * S_ + t * 64 + gsw * 8;
      GLOAD_LDS16(vsrc, &Vt[buf][r0][0]);
    }
  };

  const f32x4 zero4 = {0.f, 0.f, 0.f, 0.f};
  f32x4 acc[2][4];
#pragma unroll
  for (int mt = 0; mt < 2; ++mt)
#pragma unroll
    for (int et = 0; et < 4; ++et) acc[mt][et] = zero4;
  f32x4 rs4[2] = {zero4, zero4};

  // ---- one tile: QK^T -> masked exp2 -> PV (16x16x32 permuted-k)
  auto tilec = [&](int buf, unsigned long long mw) {
    // S^T = K Q^T  (A: swizzled Ks rows b128; B: pre-scaled Q regs)
    f32x4 sc[4][2];
    const _Float16* kb0 = &Ks[buf][0][0];
#pragma unroll
    for (int nt = 0; nt < 4; ++nt) {
      const _Float16* krow = kb0 + (nt * 16 + cl) * 64;
      const f16x8 a0 = *(const f16x8*)(krow + ((qd ^ sw) << 3));
      const f16x8 a1 = *(const f16x8*)(krow + (((qd + 4) ^ sw) << 3));
#pragma unroll
      for (int mt = 0; mt < 2; ++mt) {
        f32x4 c = zero4;
        c = __builtin_amdgcn_mfma_f32_16x16x32_f16(a0, qf[mt][0], c, 0, 0, 0);
        c = __builtin_amdgcn_mfma_f32_16x16x32_f16(a1, qf[mt][1], c, 0, 0, 0);
        sc[nt][mt] = c;  // q = mt*16+cl, s = nt*16 + qd*4 + r
      }
    }

    // softmax numerator; P packed directly as 16x16x32 A-frag halves
    H8 pa8[2][2];  // [mt][ntp]: slots 0-3 = block 2ntp, slots 4-7 = block 2ntp+1
    if (mw == ~0ull) {  // all-attend fast path (Q pre-scaled: exp2 direct)
#pragma unroll
      for (int mt = 0; mt < 2; ++mt)
#pragma unroll
        for (int nt = 0; nt < 4; ++nt) {
          f32x4 p;
#pragma unroll
          for (int r = 0; r < 4; ++r)
            p[r] = __builtin_amdgcn_exp2f(sc[nt][mt][r]);
          rs4[mt] += p;
          H4 u;
          u.h[0] = cvt2(p[0], p[1]);
          u.h[1] = cvt2(p[2], p[3]);
          pa8[mt][nt >> 1].h4[nt & 1] = u.v;
        }
    } else {
      // bit for s = nt*16+qd*4+r sits at p = 16r + 4nt + qd
      const unsigned lo = (unsigned)mw;
      const unsigned hi = (unsigned)(mw >> 32);
#pragma unroll
      for (int mt = 0; mt < 2; ++mt)
#pragma unroll
        for (int nt = 0; nt < 4; ++nt) {
          const unsigned m0 = lo >> (4 * nt + qd);  // r=0 bit0, r=1 bit16
          const unsigned m1 = hi >> (4 * nt + qd);  // r=2 bit0, r=3 bit16
          f32x4 p;
          p[0] = __builtin_amdgcn_exp2f(sc[nt][mt][0] + ((m0 & 1u)       ? 0.f : MBIAS2f));
          p[1] = __builtin_amdgcn_exp2f(sc[nt][mt][1] + ((m0 & 0x10000u) ? 0.f : MBIAS2f));
          p[2] = __builtin_amdgcn_exp2f(sc[nt][mt][2] + ((m1 & 1u)       ? 0.f : MBIAS2f));
          p[3] = __builtin_amdgcn_exp2f(sc[nt][mt][3] + ((m1 & 0x10000u) ? 0.f : MBIAS2f));
          rs4[mt] += p;
          H4 u;
          u.h[0] = cvt2(p[0], p[1]);
          u.h[1] = cvt2(p[2], p[3]);
          pa8[mt][nt >> 1].h4[nt & 1] = u.v;
        }
    }

    // O += P V at 16x16x32: interleaved Vt -> one b128 B-frag per MFMA
    const _Float16* vb0 = &Vt[buf][0][0];
#pragma unroll
    for (int ntp = 0; ntp < 2; ++ntp)
#pragma unroll
      for (int et = 0; et < 4; ++et) {
        const _Float16* vrow = vb0 + (et * 16 + cl) * 64;
        const f16x8 bv = *(const f16x8*)(vrow + (((ntp * 4 + qd) ^ sw) << 3));
        acc[0][et] = __builtin_amdgcn_mfma_f32_16x16x32_f16(pa8[0][ntp].v, bv, acc[0][et], 0, 0, 0);
        acc[1][et] = __builtin_amdgcn_mfma_f32_16x16x32_f16(pa8[1][ntp].v, bv, acc[1][et], 0, 0, 0);
      }
  };

  // ---- prologue: pairs 0 and 1 (10 VMEM each: 2 mask + 8 gload_lds)
  unsigned long long m0 = wbp[0], m1 = wbp[1];
  dma(0, 0);
  dma(1, 1);
  asm volatile("" ::: "memory");  // region boundary
  unsigned long long m2 = wbp[2], m3 = wbp[3];
  dma(2, 2);
  dma(3, 3);
  asm volatile("" ::: "memory");

  for (int p = 0; p < NPAIRS; ++p) {
    // pair p landed; pair p+1 (10 ops) stays in flight
    if (p < NPAIRS - 1)
      asm volatile("s_waitcnt vmcnt(10)" ::: "memory");
    else
      asm volatile("s_waitcnt vmcnt(0)" ::: "memory");
    __builtin_amdgcn_s_barrier();  // A: pair p consumable

    const int b0 = (p & 1) << 1;   // tiles 2p,2p+1 in bufs {b0, b0+1}
    tilec(b0, m0);
    tilec(b0 + 1, m1);

    unsigned long long m4 = 0, m5 = 0;
    if (p + 2 < NPAIRS) {
      __builtin_amdgcn_s_barrier();  // B: all waves done reading pair p
      m4 = wbp[2 * p + 4];
      m5 = wbp[2 * p + 5];
      dma(b0, 2 * p + 4);            // pair p+2 reuses pair p's slots
      dma(b0 + 1, 2 * p + 5);
      asm volatile("" ::: "memory");  // region boundary
    }
    m0 = m2; m1 = m3; m2 = m4; m3 = m5;
  }

  // ---- epilogue: row-sum reduce, broadcast inv per q-row, store
#pragma unroll
  for (int mt = 0; mt < 2; ++mt) {
    float v = rs4[mt][0] + rs4[mt][1] + rs4[mt][2] + rs4[mt][3];
    v += __shfl_xor(v, 16, 64);
    v += __shfl_xor(v, 32, 64);  // every lane: sum for q = mt*16 + cl
#pragma unroll
    for (int r = 0; r < 4; ++r) {
      const float invq = 1.0f / __shfl(v, qd * 4 + r, 64);
      const int l = l0 + mt * 16 + qd * 4 + r;
      float* op = Og + ((((size_t)b * H_ + h) * L_ + l) << 6) + cl;
#pragma unroll
      for (int et = 0; et < 4; ++et) op[et * 16] = acc[mt][et][r] * invq;
    }
  }
}

extern "C" void kernel_launch(void* const* d_in, const int* in_sizes, int n_in,
                              void* d_out, int out_size, void* d_ws, size_t ws_size,
                              hipStream_t stream) {
  const float* Q = (const float*)d_in[0];
  const float* K = (const float*)d_in[1];
  const float* V = (const float*)d_in[2];
  const float* M = (const float*)d_in[3];
  float* O = (float*)d_out;
  unsigned long long* Wb = (unsigned long long*)d_ws;              // 1 MiB
  _Float16* Khp = (_Float16*)((char*)d_ws + KHOFF);                // 8.39 MB
  _Float16* Vhp = (_Float16*)((char*)d_ws + VHOFF);                // 8.39 MB

  hipLaunchKernelGGL(prep_kernel, dim3(5120), dim3(256), 0, stream, K, V, M, Khp, Vhp, Wb);
  hipLaunchKernelGGL(fattn_kernel, dim3(B_ * H_ * (L_ / MBLK)), dim3(256), 0, stream,
                     Q, Khp, Vhp, Wb, O);
}